// Round 11
// baseline (475.817 us; speedup 1.0000x reference)
//
#include <hip/hip_runtime.h>
#include <hip/hip_bf16.h>
#include <stdint.h>

typedef unsigned short u16;
typedef __bf16 bf16_8 __attribute__((ext_vector_type(8)));
typedef float f32x4 __attribute__((ext_vector_type(4)));

#define SEQ 2048
#define DIM 4096
#define NH 32
#define NKV 8
#define HD 128
// 1/sqrt(128) * log2(e)  -- exp2-based softmax, scale folded into Q epilogue
#define QSCALE_LOG2E 0.12753785222167917f

__device__ inline u16 f2bf(float f) {
    unsigned int u = __float_as_uint(f);
    unsigned int r = (u + 0x7fffu + ((u >> 16) & 1u)) >> 16;
    return (u16)r;
}

__device__ inline void async16(const void* g, void* l) {
    __builtin_amdgcn_global_load_lds(
        (const __attribute__((address_space(1))) void*)g,
        (__attribute__((address_space(3))) void*)l, 16, 0, 0);
}

// ---------------- fused fp32 -> bf16 cast of all 5 tensors ----------------
__global__ __launch_bounds__(256) void cast_all(const float* __restrict__ x,
                                                const float* __restrict__ wq,
                                                const float* __restrict__ wk,
                                                const float* __restrict__ wv,
                                                const float* __restrict__ wo,
                                                u16* __restrict__ dst) {
    size_t i4 = (size_t)blockIdx.x * 256 + threadIdx.x;  // float4 group index
    size_t e = i4 * 4;                                   // element index
    const float* src;
    size_t off;  // segment start (elements)
    if (e < 8388608ull)       { src = x;  off = 0; }
    else if (e < 25165824ull) { src = wq; off = 8388608ull; }
    else if (e < 29360128ull) { src = wk; off = 25165824ull; }
    else if (e < 33554432ull) { src = wv; off = 29360128ull; }
    else                      { src = wo; off = 33554432ull; }
    float4 v = ((const float4*)src)[i4 - off / 4];
    ushort4 o;
    o.x = f2bf(v.x); o.y = f2bf(v.y); o.z = f2bf(v.z); o.w = f2bf(v.w);
    ((ushort4*)dst)[i4] = o;
}

// ============ GEMM core: C[M,N] = A[M,K] * B[N,K]^T (bf16, fp32 acc) =======
// BK=64 single-buffer m97-class structure (round-9: 130 us/dispatch, QKV
// ~791 TF, MfmaUtil 35%, 0 bank conflicts, FETCH ~90 MB).  UNCHANGED.
// MODE 0: fp32 row-major out (out-proj)
// MODE 1: QKV-routed epilogue with fused RoPE (Q pre-scaled by QSCALE_LOG2E)
template <int MODE>
__global__ __launch_bounds__(256) void gemm_bt(const u16* __restrict__ A,
                                               const u16* __restrict__ B,
                                               void* __restrict__ C0,
                                               void* __restrict__ C1,
                                               void* __restrict__ C2,
                                               const float* __restrict__ fc,
                                               const float* __restrict__ fs,
                                               int M, int N, int K) {
    __shared__ u16 As[128 * 64];
    __shared__ u16 Bs[128 * 64];
    const int tid = threadIdx.x;
    const int lane = tid & 63;
    const int wid = tid >> 6;
    const int quad = lane >> 4;
    const int l16 = lane & 15;
    const int wm = (wid >> 1) * 64;
    const int wn = (wid & 1) * 64;

    // ---- 2D XCD partition (bijective; gy%2==0, gx%4==0 for both grids).
    const int gx = gridDim.x, gy = gridDim.y;
    int id = blockIdx.y * gx + blockIdx.x;
    const int xcd = id & 7;
    const int j = id >> 3;
    const int hy = gy >> 1;
    const int jm = j % hy;
    const int jn = j / hy;
    const int bm = ((xcd >> 2) * hy + jm) * 128;
    const int bn = ((xcd & 3) * (gx >> 2) + jn) * 128;

    f32x4 acc[4][4] = {};

    for (int k0 = 0; k0 < K; k0 += 64) {
        // stage 128x64 A and B tiles: 4 async16 each per thread
#pragma unroll
        for (int r = 0; r < 4; ++r) {
            int S = r * 256 + tid;          // chunk slot 0..1023
            int row = S >> 3;
            int slot = S & 7;
            int chunk = slot ^ (row & 7);
            const char* ga = (const char*)A + ((size_t)(bm + row) * K + k0 + chunk * 8) * 2;
            async16(ga, (char*)As + S * 16);
            const char* gb = (const char*)B + ((size_t)(bn + row) * K + k0 + chunk * 8) * 2;
            async16(gb, (char*)Bs + S * 16);
        }
        __syncthreads();
#pragma unroll
        for (int ks = 0; ks < 2; ++ks) {
            const int cs = (ks * 4 + quad) ^ (l16 & 7);  // swizzled chunk slot
            bf16_8 a[4], b[4];
#pragma unroll
            for (int i = 0; i < 4; ++i)
                a[i] = *(const bf16_8*)&As[(wm + i * 16 + l16) * 64 + cs * 8];
#pragma unroll
            for (int j2 = 0; j2 < 4; ++j2)
                b[j2] = *(const bf16_8*)&Bs[(wn + j2 * 16 + l16) * 64 + cs * 8];
#pragma unroll
            for (int i = 0; i < 4; ++i)
#pragma unroll
                for (int j2 = 0; j2 < 4; ++j2)
                    acc[i][j2] = __builtin_amdgcn_mfma_f32_16x16x32_bf16(a[i], b[j2], acc[i][j2], 0, 0, 0);
        }
        __syncthreads();
    }

    if (MODE == 0) {
        float* Cf = (float*)C0;
#pragma unroll
        for (int i = 0; i < 4; ++i)
#pragma unroll
            for (int j2 = 0; j2 < 4; ++j2)
#pragma unroll
                for (int r = 0; r < 4; ++r)
                    Cf[(size_t)(bm + wm + i * 16 + quad * 4 + r) * N + (bn + wn + j2 * 16 + l16)] =
                        acc[i][j2][r];
    } else {
        // QKV routing; bn is a multiple of 128 so the whole block takes one branch
        u16* Qb = (u16*)C0;
        u16* Kb = (u16*)C1;
        u16* Vt = (u16*)C2;
        if (bn < 5120) {
            const bool isQ = bn < 4096;
            const float osc = isQ ? QSCALE_LOG2E : 1.0f;
#pragma unroll
            for (int i = 0; i < 4; ++i)
#pragma unroll
                for (int j2 = 0; j2 < 4; ++j2) {
                    int n = bn + wn + j2 * 16 + l16;
                    int pp = (n & 127) >> 1;
                    bool odd = (l16 & 1);
#pragma unroll
                    for (int r = 0; r < 4; ++r) {
                        int m = bm + wm + i * 16 + quad * 4 + r;
                        float v = acc[i][j2][r];
                        float u = __shfl_xor(v, 1);
                        float c = fc[m * 64 + pp];
                        float s = fs[m * 64 + pp];
                        float o = (odd ? (u * s + v * c) : (v * c - u * s)) * osc;
                        if (isQ)
                            Qb[(size_t)m * 4096 + n] = f2bf(o);
                        else
                            Kb[(size_t)m * 1024 + (n - 4096)] = f2bf(o);
                    }
                }
        } else {
            // V range: store transposed (d-major), no rope
#pragma unroll
            for (int i = 0; i < 4; ++i)
#pragma unroll
                for (int j2 = 0; j2 < 4; ++j2) {
                    int n = bn + wn + j2 * 16 + l16;
                    ushort4 o;
                    o.x = f2bf(acc[i][j2][0]);
                    o.y = f2bf(acc[i][j2][1]);
                    o.z = f2bf(acc[i][j2][2]);
                    o.w = f2bf(acc[i][j2][3]);
                    *(ushort4*)&Vt[(size_t)(n - 5120) * SEQ + (bm + wm + i * 16 + quad * 4)] = o;
                }
        }
    }
}

// ---------------- Flash attention, S^T formulation ----------------
// Round-10/11 change (ONLY the block->work mapping): kv-head-per-XCD remap.
// 8 kv-heads == 8 XCDs.  HW round-robins consecutive block ids over XCDs
// (xcd = id&7, mechanism validated by the GEMM 2D partition).  Old mapping
// (h = id&31) put 4 distinct kv-heads' K/V (4 MB) on every XCD = exactly the
// 4 MB L2 -> thrash -> every 32 KB tile stage paid HBM latency (T_tile
// ~12000 cyc inferred).  New mapping: kvh = id&7 -> each XCD touches exactly
// ONE kv-head (K+V = 1 MB, L2-resident after first touch); qt LPT preserved
// within each XCD (all 128 blocks/XCD co-resident at 4 blocks/CU anyway).
__global__ __launch_bounds__(256, 4) void attn_k(const u16* __restrict__ Q,
                                                 const u16* __restrict__ Kb,
                                                 const u16* __restrict__ Vt,
                                                 u16* __restrict__ Y) {
    __shared__ u16 Ks[64 * 128];   // swizzled: 16B chunks, slot = c ^ (row&15)
    __shared__ u16 Vs[128 * 64];   // swizzled: 16B chunks, slot = c ^ (row&7)
    __shared__ u16 Ps[4 * 16 * 64];// per-wave 2 KB; 8B chunks, c' = c ^ ((l16&7)<<1)
    const int tid = threadIdx.x;
    const int lane = tid & 63;
    const int w = tid >> 6;
    const int quad = lane >> 4;
    const int l16 = lane & 15;
    const int id = blockIdx.x;
    const int kvh = id & 7;          // == XCD (id round-robin over 8 XCDs)
    const int rblk = id >> 3;        // 0..127 within this XCD
    const int qh = rblk & 3;         // q-head within kv-head
    const int qt = 31 - (rblk >> 2); // LPT: longest blocks first
    const int h = kvh * 4 + qh;      // h>>2 == kvh (consistent with layout)
    const size_t qrow0 = (size_t)qt * 64;

    bf16_8 qf[4];
#pragma unroll
    for (int ks = 0; ks < 4; ++ks)
        qf[ks] = *(const bf16_8*)&Q[(qrow0 + w * 16 + l16) * DIM + h * HD + ks * 32 + quad * 8];

    f32x4 po[8] = {};    // 16 x 128 unnormalized output accumulator
    float lsum = 0.f;    // per-lane partial row sum for q-row l16

    char* psbase = (char*)Ps + w * 2048 + l16 * 128;  // this lane's P row
    const int sw = (l16 & 7) << 1;                    // 8B-chunk swizzle

    for (int kt = 0; kt <= qt; ++kt) {
#pragma unroll
        for (int r = 0; r < 4; ++r) {
            int S = r * 256 + tid;  // 0..1023
            {
                int row = S >> 4, slot = S & 15;
                int chunk = slot ^ (row & 15);
                const char* g = (const char*)Kb +
                    (((size_t)kt * 64 + row) * 1024 + kvh * HD + chunk * 8) * 2;
                async16(g, (char*)Ks + S * 16);
            }
            {
                int row = S >> 3, slot = S & 7;
                int chunk = slot ^ (row & 7);
                const char* g = (const char*)Vt +
                    (((size_t)(kvh * HD + row)) * SEQ + kt * 64 + chunk * 8) * 2;
                async16(g, (char*)Vs + S * 16);
            }
        }
        __syncthreads();

        f32x4 sc[4] = {};
#pragma unroll
        for (int ks = 0; ks < 4; ++ks)
#pragma unroll
            for (int jb = 0; jb < 4; ++jb) {
                bf16_8 kb = *(const bf16_8*)&Ks[(jb * 16 + l16) * 128 + ((ks * 4 + quad) ^ l16) * 8];
                sc[jb] = __builtin_amdgcn_mfma_f32_16x16x32_bf16(kb, qf[ks], sc[jb], 0, 0, 0);
            }

        float pv[4][4];
#pragma unroll
        for (int jb = 0; jb < 4; ++jb)
#pragma unroll
            for (int r = 0; r < 4; ++r)
                pv[jb][r] = exp2f(sc[jb][r]);

        if (kt == qt) {  // wave-uniform: mask k > q on the diagonal tile
            int qloc = w * 16 + l16;
#pragma unroll
            for (int jb = 0; jb < 4; ++jb)
#pragma unroll
                for (int r = 0; r < 4; ++r)
                    if (jb * 16 + quad * 4 + r > qloc) pv[jb][r] = 0.f;
        }

#pragma unroll
        for (int jb = 0; jb < 4; ++jb) {
            lsum += (pv[jb][0] + pv[jb][1]) + (pv[jb][2] + pv[jb][3]);
            ushort4 pk;
            pk.x = f2bf(pv[jb][0]);
            pk.y = f2bf(pv[jb][1]);
            pk.z = f2bf(pv[jb][2]);
            pk.w = f2bf(pv[jb][3]);
            int c = jb * 4 + quad;
            *(ushort4*)(psbase + ((c ^ sw) << 3)) = pk;
        }

#pragma unroll
        for (int ks = 0; ks < 2; ++ks) {
            int c = ks * 8 + quad * 2;
            bf16_8 pf = *(const bf16_8*)(psbase + ((c ^ sw) << 3));
#pragma unroll
            for (int n = 0; n < 8; ++n) {
                bf16_8 vf = *(const bf16_8*)&Vs[(n * 16 + l16) * 64 + (((ks * 4 + quad) ^ (l16 & 7))) * 8];
                po[n] = __builtin_amdgcn_mfma_f32_16x16x32_bf16(pf, vf, po[n], 0, 0, 0);
            }
        }
        __syncthreads();
    }

    lsum += __shfl_xor(lsum, 16);
    lsum += __shfl_xor(lsum, 32);
    float inv = 1.f / lsum;
#pragma unroll
    for (int r = 0; r < 4; ++r) {
        float invr = __shfl(inv, quad * 4 + r);
        size_t row = qrow0 + w * 16 + quad * 4 + r;
#pragma unroll
        for (int n = 0; n < 8; ++n)
            Y[row * DIM + h * HD + n * 16 + l16] = f2bf(po[n][r] * invr);
    }
}

extern "C" void kernel_launch(void* const* d_in, const int* in_sizes, int n_in,
                              void* d_out, int out_size, void* d_ws, size_t ws_size,
                              hipStream_t stream) {
    const float* x  = (const float*)d_in[0];
    const float* wq = (const float*)d_in[1];
    const float* wk = (const float*)d_in[2];
    const float* wv = (const float*)d_in[3];
    const float* wo = (const float*)d_in[4];
    const float* fc = (const float*)d_in[5];
    const float* fs = (const float*)d_in[6];

    char* ws = (char*)d_ws;
    const size_t MB = 1u << 20;
    u16* xb    = (u16*)(ws);             // 2048x4096 bf16       (16 MB)
    u16* wqkvb = (u16*)(ws + 16 * MB);   // 6144x4096 (wq|wk|wv) (48 MB)
    u16* wob   = (u16*)(ws + 64 * MB);   // 4096x4096            (32 MB)
    u16* Qb    = (u16*)(ws + 96 * MB);   // 2048x4096            (16 MB)
    u16* Kb    = (u16*)(ws + 112 * MB);  // 2048x1024            (4 MB)
    u16* Vtb   = (u16*)(ws + 116 * MB);  // 1024x2048 (V^T)      (4 MB)
    u16* Yb    = (u16*)(ws + 120 * MB);  // 2048x4096            (16 MB)

    // single fused cast: [x | wq | wk | wv | wo] -> bf16 at ws[0..96MB)
    cast_all<<<49152, 256, 0, stream>>>(x, wq, wk, wv, wo, (u16*)ws);

    // fused QKV projection + RoPE (+ Q pre-scale incl. log2e) epilogue
    gemm_bt<1><<<dim3(48, 16), 256, 0, stream>>>(xb, wqkvb, Qb, Kb, Vtb, fc, fs,
                                                 2048, 6144, 4096);

    // attention (kv-head-per-XCD 1D grid, LPT within XCD)
    attn_k<<<dim3(1024), 256, 0, stream>>>(Qb, Kb, Vtb, Yb);

    // output projection -> fp32 d_out
    gemm_bt<0><<<dim3(32, 16), 256, 0, stream>>>(Yb, wob, (float*)d_out, nullptr, nullptr,
                                                 nullptr, nullptr, 2048, 4096, 4096);
}

// Round 12
// 473.920 us; speedup vs baseline: 1.0040x; 1.0040x over previous
//
#include <hip/hip_runtime.h>
#include <hip/hip_bf16.h>
#include <stdint.h>

typedef unsigned short u16;
typedef __bf16 bf16_8 __attribute__((ext_vector_type(8)));
typedef float f32x4 __attribute__((ext_vector_type(4)));

#define SEQ 2048
#define DIM 4096
#define NH 32
#define NKV 8
#define HD 128
// 1/sqrt(128) * log2(e)  -- exp2-based softmax, scale folded into Q epilogue
#define QSCALE_LOG2E 0.12753785222167917f

__device__ inline u16 f2bf(float f) {
    unsigned int u = __float_as_uint(f);
    unsigned int r = (u + 0x7fffu + ((u >> 16) & 1u)) >> 16;
    return (u16)r;
}

__device__ inline void async16(const void* g, void* l) {
    __builtin_amdgcn_global_load_lds(
        (const __attribute__((address_space(1))) void*)g,
        (__attribute__((address_space(3))) void*)l, 16, 0, 0);
}

// ---------------- fused fp32 -> bf16 cast of all 5 tensors ----------------
__global__ __launch_bounds__(256) void cast_all(const float* __restrict__ x,
                                                const float* __restrict__ wq,
                                                const float* __restrict__ wk,
                                                const float* __restrict__ wv,
                                                const float* __restrict__ wo,
                                                u16* __restrict__ dst) {
    size_t i4 = (size_t)blockIdx.x * 256 + threadIdx.x;  // float4 group index
    size_t e = i4 * 4;                                   // element index
    const float* src;
    size_t off;  // segment start (elements)
    if (e < 8388608ull)       { src = x;  off = 0; }
    else if (e < 25165824ull) { src = wq; off = 8388608ull; }
    else if (e < 29360128ull) { src = wk; off = 25165824ull; }
    else if (e < 33554432ull) { src = wv; off = 29360128ull; }
    else                      { src = wo; off = 33554432ull; }
    float4 v = ((const float4*)src)[i4 - off / 4];
    ushort4 o;
    o.x = f2bf(v.x); o.y = f2bf(v.y); o.z = f2bf(v.z); o.w = f2bf(v.w);
    ((ushort4*)dst)[i4] = o;
}

// ============ GEMM core: C[M,N] = A[M,K] * B[N,K]^T (bf16, fp32 acc) =======
// BK=64 single-buffer m97-class structure (round-9/11: ~128 us/dispatch, QKV
// ~791 TF, MfmaUtil 35%, 0 bank conflicts, FETCH ~90 MB).  UNCHANGED.
// MODE 0: fp32 row-major out (out-proj)
// MODE 1: QKV-routed epilogue with fused RoPE (Q pre-scaled by QSCALE_LOG2E)
template <int MODE>
__global__ __launch_bounds__(256) void gemm_bt(const u16* __restrict__ A,
                                               const u16* __restrict__ B,
                                               void* __restrict__ C0,
                                               void* __restrict__ C1,
                                               void* __restrict__ C2,
                                               const float* __restrict__ fc,
                                               const float* __restrict__ fs,
                                               int M, int N, int K) {
    __shared__ u16 As[128 * 64];
    __shared__ u16 Bs[128 * 64];
    const int tid = threadIdx.x;
    const int lane = tid & 63;
    const int wid = tid >> 6;
    const int quad = lane >> 4;
    const int l16 = lane & 15;
    const int wm = (wid >> 1) * 64;
    const int wn = (wid & 1) * 64;

    // ---- 2D XCD partition (bijective; gy%2==0, gx%4==0 for both grids).
    const int gx = gridDim.x, gy = gridDim.y;
    int id = blockIdx.y * gx + blockIdx.x;
    const int xcd = id & 7;
    const int j = id >> 3;
    const int hy = gy >> 1;
    const int jm = j % hy;
    const int jn = j / hy;
    const int bm = ((xcd >> 2) * hy + jm) * 128;
    const int bn = ((xcd & 3) * (gx >> 2) + jn) * 128;

    f32x4 acc[4][4] = {};

    for (int k0 = 0; k0 < K; k0 += 64) {
        // stage 128x64 A and B tiles: 4 async16 each per thread
#pragma unroll
        for (int r = 0; r < 4; ++r) {
            int S = r * 256 + tid;          // chunk slot 0..1023
            int row = S >> 3;
            int slot = S & 7;
            int chunk = slot ^ (row & 7);
            const char* ga = (const char*)A + ((size_t)(bm + row) * K + k0 + chunk * 8) * 2;
            async16(ga, (char*)As + S * 16);
            const char* gb = (const char*)B + ((size_t)(bn + row) * K + k0 + chunk * 8) * 2;
            async16(gb, (char*)Bs + S * 16);
        }
        __syncthreads();
#pragma unroll
        for (int ks = 0; ks < 2; ++ks) {
            const int cs = (ks * 4 + quad) ^ (l16 & 7);  // swizzled chunk slot
            bf16_8 a[4], b[4];
#pragma unroll
            for (int i = 0; i < 4; ++i)
                a[i] = *(const bf16_8*)&As[(wm + i * 16 + l16) * 64 + cs * 8];
#pragma unroll
            for (int j2 = 0; j2 < 4; ++j2)
                b[j2] = *(const bf16_8*)&Bs[(wn + j2 * 16 + l16) * 64 + cs * 8];
#pragma unroll
            for (int i = 0; i < 4; ++i)
#pragma unroll
                for (int j2 = 0; j2 < 4; ++j2)
                    acc[i][j2] = __builtin_amdgcn_mfma_f32_16x16x32_bf16(a[i], b[j2], acc[i][j2], 0, 0, 0);
        }
        __syncthreads();
    }

    if (MODE == 0) {
        float* Cf = (float*)C0;
#pragma unroll
        for (int i = 0; i < 4; ++i)
#pragma unroll
            for (int j2 = 0; j2 < 4; ++j2)
#pragma unroll
                for (int r = 0; r < 4; ++r)
                    Cf[(size_t)(bm + wm + i * 16 + quad * 4 + r) * N + (bn + wn + j2 * 16 + l16)] =
                        acc[i][j2][r];
    } else {
        // QKV routing; bn is a multiple of 128 so the whole block takes one branch
        u16* Qb = (u16*)C0;
        u16* Kb = (u16*)C1;
        u16* Vt = (u16*)C2;
        if (bn < 5120) {
            const bool isQ = bn < 4096;
            const float osc = isQ ? QSCALE_LOG2E : 1.0f;
#pragma unroll
            for (int i = 0; i < 4; ++i)
#pragma unroll
                for (int j2 = 0; j2 < 4; ++j2) {
                    int n = bn + wn + j2 * 16 + l16;
                    int pp = (n & 127) >> 1;
                    bool odd = (l16 & 1);
#pragma unroll
                    for (int r = 0; r < 4; ++r) {
                        int m = bm + wm + i * 16 + quad * 4 + r;
                        float v = acc[i][j2][r];
                        float u = __shfl_xor(v, 1);
                        float c = fc[m * 64 + pp];
                        float s = fs[m * 64 + pp];
                        float o = (odd ? (u * s + v * c) : (v * c - u * s)) * osc;
                        if (isQ)
                            Qb[(size_t)m * 4096 + n] = f2bf(o);
                        else
                            Kb[(size_t)m * 1024 + (n - 4096)] = f2bf(o);
                    }
                }
        } else {
            // V range: store transposed (d-major), no rope
#pragma unroll
            for (int i = 0; i < 4; ++i)
#pragma unroll
                for (int j2 = 0; j2 < 4; ++j2) {
                    int n = bn + wn + j2 * 16 + l16;
                    ushort4 o;
                    o.x = f2bf(acc[i][j2][0]);
                    o.y = f2bf(acc[i][j2][1]);
                    o.z = f2bf(acc[i][j2][2]);
                    o.w = f2bf(acc[i][j2][3]);
                    *(ushort4*)&Vt[(size_t)(n - 5120) * SEQ + (bm + wm + i * 16 + quad * 4)] = o;
                }
        }
    }
}

// ---------------- Flash attention, S^T formulation ----------------
// Round-12 change: DOUBLE-BUFFERED K/V LDS with one-tile staging lead and
// ONE barrier per tile.  Old chain (single-buffer): stage with ZERO lead ->
// __syncthreads drains vmcnt(0) = full load latency + 32KB transfer exposed
// every tile (~8k cyc/tile for ~2.5k of content; attn ~115us inferred).
// New: stage kt+1 into buf^1 BEFORE computing kt from buf; end-of-tile
// __syncthreads then (a) retires all reads of buf before iter kt+1 overwrites
// it, (b) its vmcnt(0) drain waits on loads issued one full compute phase
// (~2.5k cyc) earlier -> drain ~free.  No counted vmcnt needed: lead = 1 tile.
// Cost: LDS 40 -> 72 KB -> 2 blocks/CU (launch_bounds(256,2), VGPR cap 256).
// Bet: chain 8k -> ~4k cyc/tile beats the lost 4->2 blocks/CU stall-filling.
// kv-head-per-XCD remap kept (neutral-at-worst, helps L2 residency).
__global__ __launch_bounds__(256, 2) void attn_k(const u16* __restrict__ Q,
                                                 const u16* __restrict__ Kb,
                                                 const u16* __restrict__ Vt,
                                                 u16* __restrict__ Y) {
    __shared__ u16 Ks[2 * 64 * 128];   // dbuf; 16B chunks, slot = c ^ (row&15)
    __shared__ u16 Vs[2 * 128 * 64];   // dbuf; 16B chunks, slot = c ^ (row&7)
    __shared__ u16 Ps[4 * 16 * 64];    // per-wave 2 KB; 8B chunks, c' = c ^ ((l16&7)<<1)
    const int tid = threadIdx.x;
    const int lane = tid & 63;
    const int w = tid >> 6;
    const int quad = lane >> 4;
    const int l16 = lane & 15;
    const int id = blockIdx.x;
    const int kvh = id & 7;          // == XCD (id round-robin over 8 XCDs)
    const int rblk = id >> 3;        // 0..127 within this XCD
    const int qh = rblk & 3;         // q-head within kv-head
    const int qt = 31 - (rblk >> 2); // LPT: longest blocks first
    const int h = kvh * 4 + qh;      // h>>2 == kvh (consistent with layout)
    const size_t qrow0 = (size_t)qt * 64;

    bf16_8 qf[4];
#pragma unroll
    for (int ks = 0; ks < 4; ++ks)
        qf[ks] = *(const bf16_8*)&Q[(qrow0 + w * 16 + l16) * DIM + h * HD + ks * 32 + quad * 8];

    f32x4 po[8] = {};    // 16 x 128 unnormalized output accumulator
    float lsum = 0.f;    // per-lane partial row sum for q-row l16

    char* psbase = (char*)Ps + w * 2048 + l16 * 128;  // this lane's P row
    const int sw = (l16 & 7) << 1;                    // 8B-chunk swizzle

    // stage K/V tile kt into buffer b (8 async16/thread, chunk-swizzled)
#define STAGE(kt, b)                                                          \
    {                                                                         \
        _Pragma("unroll") for (int r = 0; r < 4; ++r) {                       \
            int S = r * 256 + tid;                                            \
            {                                                                 \
                int row = S >> 4, slot = S & 15;                              \
                int chunk = slot ^ (row & 15);                                \
                const char* g = (const char*)Kb +                             \
                    (((size_t)(kt) * 64 + row) * 1024 + kvh * HD + chunk * 8) * 2; \
                async16(g, (char*)Ks + (b) * 16384 + S * 16);                 \
            }                                                                 \
            {                                                                 \
                int row = S >> 3, slot = S & 7;                               \
                int chunk = slot ^ (row & 7);                                 \
                const char* g = (const char*)Vt +                             \
                    (((size_t)(kvh * HD + row)) * SEQ + (kt) * 64 + chunk * 8) * 2; \
                async16(g, (char*)Vs + (b) * 16384 + S * 16);                 \
            }                                                                 \
        }                                                                     \
    }

    STAGE(0, 0);
    __syncthreads();

    for (int kt = 0; kt <= qt; ++kt) {
        const int b = kt & 1;
        if (kt < qt) STAGE(kt + 1, b ^ 1);   // issue next tile FIRST: 1-tile lead
        const u16* ks_b = Ks + b * 8192;
        const u16* vs_b = Vs + b * 8192;

        f32x4 sc[4] = {};
#pragma unroll
        for (int ks = 0; ks < 4; ++ks)
#pragma unroll
            for (int jb = 0; jb < 4; ++jb) {
                bf16_8 kb = *(const bf16_8*)&ks_b[(jb * 16 + l16) * 128 + ((ks * 4 + quad) ^ l16) * 8];
                sc[jb] = __builtin_amdgcn_mfma_f32_16x16x32_bf16(kb, qf[ks], sc[jb], 0, 0, 0);
            }

        float pv[4][4];
#pragma unroll
        for (int jb = 0; jb < 4; ++jb)
#pragma unroll
            for (int r = 0; r < 4; ++r)
                pv[jb][r] = exp2f(sc[jb][r]);

        if (kt == qt) {  // wave-uniform: mask k > q on the diagonal tile
            int qloc = w * 16 + l16;
#pragma unroll
            for (int jb = 0; jb < 4; ++jb)
#pragma unroll
                for (int r = 0; r < 4; ++r)
                    if (jb * 16 + quad * 4 + r > qloc) pv[jb][r] = 0.f;
        }

#pragma unroll
        for (int jb = 0; jb < 4; ++jb) {
            lsum += (pv[jb][0] + pv[jb][1]) + (pv[jb][2] + pv[jb][3]);
            ushort4 pk;
            pk.x = f2bf(pv[jb][0]);
            pk.y = f2bf(pv[jb][1]);
            pk.z = f2bf(pv[jb][2]);
            pk.w = f2bf(pv[jb][3]);
            int c = jb * 4 + quad;
            *(ushort4*)(psbase + ((c ^ sw) << 3)) = pk;
        }

#pragma unroll
        for (int ks = 0; ks < 2; ++ks) {
            int c = ks * 8 + quad * 2;
            bf16_8 pf = *(const bf16_8*)(psbase + ((c ^ sw) << 3));
#pragma unroll
            for (int n = 0; n < 8; ++n) {
                bf16_8 vf = *(const bf16_8*)&vs_b[(n * 16 + l16) * 64 + (((ks * 4 + quad) ^ (l16 & 7))) * 8];
                po[n] = __builtin_amdgcn_mfma_f32_16x16x32_bf16(pf, vf, po[n], 0, 0, 0);
            }
        }
        // single barrier: retires reads of buf b (overwritten next iter) and
        // drains the STAGE(kt+1) loads issued before this tile's compute.
        __syncthreads();
    }
#undef STAGE

    lsum += __shfl_xor(lsum, 16);
    lsum += __shfl_xor(lsum, 32);
    float inv = 1.f / lsum;
#pragma unroll
    for (int r = 0; r < 4; ++r) {
        float invr = __shfl(inv, quad * 4 + r);
        size_t row = qrow0 + w * 16 + quad * 4 + r;
#pragma unroll
        for (int n = 0; n < 8; ++n)
            Y[row * DIM + h * HD + n * 16 + l16] = f2bf(po[n][r] * invr);
    }
}

extern "C" void kernel_launch(void* const* d_in, const int* in_sizes, int n_in,
                              void* d_out, int out_size, void* d_ws, size_t ws_size,
                              hipStream_t stream) {
    const float* x  = (const float*)d_in[0];
    const float* wq = (const float*)d_in[1];
    const float* wk = (const float*)d_in[2];
    const float* wv = (const float*)d_in[3];
    const float* wo = (const float*)d_in[4];
    const float* fc = (const float*)d_in[5];
    const float* fs = (const float*)d_in[6];

    char* ws = (char*)d_ws;
    const size_t MB = 1u << 20;
    u16* xb    = (u16*)(ws);             // 2048x4096 bf16       (16 MB)
    u16* wqkvb = (u16*)(ws + 16 * MB);   // 6144x4096 (wq|wk|wv) (48 MB)
    u16* wob   = (u16*)(ws + 64 * MB);   // 4096x4096            (32 MB)
    u16* Qb    = (u16*)(ws + 96 * MB);   // 2048x4096            (16 MB)
    u16* Kb    = (u16*)(ws + 112 * MB);  // 2048x1024            (4 MB)
    u16* Vtb   = (u16*)(ws + 116 * MB);  // 1024x2048 (V^T)      (4 MB)
    u16* Yb    = (u16*)(ws + 120 * MB);  // 2048x4096            (16 MB)

    // single fused cast: [x | wq | wk | wv | wo] -> bf16 at ws[0..96MB)
    cast_all<<<49152, 256, 0, stream>>>(x, wq, wk, wv, wo, (u16*)ws);

    // fused QKV projection + RoPE (+ Q pre-scale incl. log2e) epilogue
    gemm_bt<1><<<dim3(48, 16), 256, 0, stream>>>(xb, wqkvb, Qb, Kb, Vtb, fc, fs,
                                                 2048, 6144, 4096);

    // attention (kv-head-per-XCD 1D grid, LPT within XCD, dbuf pipeline)
    attn_k<<<dim3(1024), 256, 0, stream>>>(Qb, Kb, Vtb, Yb);

    // output projection -> fp32 d_out
    gemm_bt<0><<<dim3(32, 16), 256, 0, stream>>>(Yb, wob, (float*)d_out, nullptr, nullptr,
                                                 nullptr, nullptr, 2048, 4096, 4096);
}